// Round 15
// baseline (138.691 us; speedup 1.0000x reference)
//
#include <hip/hip_runtime.h>

// Problem constants (fixed by setup_inputs)
constexpr int B_  = 8;
constexpr int NI  = 4096;
constexpr int NT  = 512;
constexpr int CD  = 1024;

constexpr int BM   = 128;       // img rows per block
constexpr int BK   = 32;        // K per tile = one mfma k-step
constexpr int NKT  = CD / BK;   // 32 K-tiles
constexpr int MAXC = 512;       // candidate list capacity per block
constexpr float DELTA = 0.02f;  // ~50 sigma of fp16 approx error; mean top-2 gap ~0.28

typedef __attribute__((ext_vector_type(4))) float    f32x4;
typedef __attribute__((ext_vector_type(8))) _Float16 f16x8;

// workspace layout: [inv_norm 16K][sidx 128K][wsB 8M]
constexpr size_t WS_NORM_B = 16384;
constexpr size_t WS_IDX_B  = (size_t)B_ * NI * 4;        // 131072
constexpr size_t WSB_OFF   = WS_NORM_B + WS_IDX_B;
constexpr size_t WSB_BYTES = (size_t)B_ * NT * CD * 2;   // 8 MB fp16 text, chunk+q major
constexpr size_t NEED_FULL = WSB_OFF + WSB_BYTES;

__device__ __forceinline__ void gl_lds16(const void* g, void* l) {
    __builtin_amdgcn_global_load_lds(
        (const __attribute__((address_space(1))) unsigned int*)g,
        (__attribute__((address_space(3))) unsigned int*)l,
        16, 0, 0);
}

__device__ __forceinline__ f16x8 packA(float4 a, float4 b) {
    f16x8 h;
    h[0] = (_Float16)a.x; h[1] = (_Float16)a.y; h[2] = (_Float16)a.z; h[3] = (_Float16)a.w;
    h[4] = (_Float16)b.x; h[5] = (_Float16)b.y; h[6] = (_Float16)b.z; h[7] = (_Float16)b.w;
    return h;
}

// Kernel 1: inv text norms (reduce bit-identical to R1 — refine replicates R1
// fp32 values whose argmax matched np exactly, proven R3-R14) + fp16 pre-scaled
// text, chunk-major q-major: slab(b,kc) = [q:4][t:512][8 halfs] (32 KB) = the
// exact linear LDS image for the gemm's B tile.
template<bool PRE>
__global__ __launch_bounds__(256) void prep_text_kernel(const float* __restrict__ text,
                                                        float* __restrict__ inv_norm,
                                                        _Float16* __restrict__ wsB) {
    int row  = blockIdx.x * 4 + (threadIdx.x >> 6);
    int lane = threadIdx.x & 63;
    const float* p = text + (size_t)row * CD;
    float s = 0.f;
#pragma unroll
    for (int it = 0; it < 4; ++it) {
        int k = (lane + it * 64) * 4;
        float4 v = *reinterpret_cast<const float4*>(p + k);
        s = fmaf(v.x, v.x, s); s = fmaf(v.y, v.y, s);
        s = fmaf(v.z, v.z, s); s = fmaf(v.w, v.w, s);
    }
#pragma unroll
    for (int off = 32; off > 0; off >>= 1) s += __shfl_xor(s, off);
    float inv = 1.f / fmaxf(sqrtf(s), 1e-12f);
    if (lane == 0) inv_norm[row] = inv;

    if (PRE) {
        int b = row >> 9, t = row & 511;
        int kc = lane >> 1;
        int q0 = (lane & 1) * 2;
        _Float16* slab = wsB + ((size_t)b * 32 + kc) * 16384;
        const float* src = p + lane * 16;
        f16x8 h0, h1;
#pragma unroll
        for (int j = 0; j < 2; ++j) {
            float4 v = *reinterpret_cast<const float4*>(src + j * 4);
            h0[j * 4 + 0] = (_Float16)(v.x * inv); h0[j * 4 + 1] = (_Float16)(v.y * inv);
            h0[j * 4 + 2] = (_Float16)(v.z * inv); h0[j * 4 + 3] = (_Float16)(v.w * inv);
        }
#pragma unroll
        for (int j = 0; j < 2; ++j) {
            float4 v = *reinterpret_cast<const float4*>(src + 8 + j * 4);
            h1[j * 4 + 0] = (_Float16)(v.x * inv); h1[j * 4 + 1] = (_Float16)(v.y * inv);
            h1[j * 4 + 2] = (_Float16)(v.z * inv); h1[j * 4 + 3] = (_Float16)(v.w * inv);
        }
        *reinterpret_cast<f16x8*>(slab + ((q0    ) * 512 + t) * 8) = h0;
        *reinterpret_cast<f16x8*>(slab + ((q0 + 1) * 512 + t) * 8) = h1;
    }
}

struct SmemM {
    _Float16 sB[3][NT * BK];    // 3 x 32 KB : [q:4][t:512][8 halfs]
    float    sA[3][BM * BK];    // 3 x 16 KB : [row][32 floats], src-XOR-swizzled
};                               // 144 KB
struct SmemE {
    float pval[4 * BM];
    int   pidx[4 * BM];
    float sval[BM];
    int   sidx[BM];
    int   rowcnt[BM];
    unsigned long long keys[BM];
    int   cand[MAXC];
    int   cnt;
};
union SmemU { SmemM m; SmemE e; };

// Kernel 2: counted-vmcnt ring-pipelined fp16 MFMA sim-GEMM (T3+T4).
//   ALL staging via global_load_lds (exactly 6/thread/tile: 4 B + 2 A) into a
//   3-buffer LDS ring; steady state keeps tiles k+1,k+2 in flight and waits
//   s_waitcnt vmcnt(6) per tile — NEVER vmcnt(0) in the main loop.
//   A: fp32, global source pre-XOR-swizzled (linear LDS dest, swizzled read —
//   rule #21); converted fp16 in-register. B: linear slab image from wsB.
// 512 thr = 8 waves (2M x 4N); wave owns 64 rows x 128 texts; grid 256 =
// 1 block/CU, batch-per-XCD. Writes per-row argmax idx (gather separate).
template<int WS>
__global__ __launch_bounds__(512, 2) void gemm_kernel(const float* __restrict__ img,
                                                      const float* __restrict__ text,
                                                      const float* __restrict__ inv_norm,
                                                      const _Float16* __restrict__ wsB,
                                                      int* __restrict__ gsidx) {
    __shared__ SmemU sm;

    const int tid = threadIdx.x;
    const int l   = tid & 63;
    const int w   = tid >> 6;
    const int wm  = w >> 2;        // 0..1 : 64-row half
    const int wn  = w & 3;         // 0..3 : 128-text slice
    const int q   = l >> 4;
    const int ln  = l & 15;

    const int b    = blockIdx.x & 7;           // batch == XCD (round-robin dispatch)
    const int row0 = (blockIdx.x >> 3) * BM;

    const float* imgBase  = img  + ((size_t)b * NI + row0) * CD;
    const float* textBase = text + (size_t)b * NT * CD;
    const char*  bSrc     = (const char*)(wsB + (size_t)b * 32 * 16384);

    // A gl_lds sources: instruction j of wave w covers LDS [ (w*2+j)*1024,
    // +1024 ) = rows (w*2+j)*8 .. +7, 128 B each. Lane -> row sub = l>>3,
    // seg = l&7; global byte pre-swizzled: (seg*16) ^ ((row&7)<<4).
    const char* aGlb[2];
#pragma unroll
    for (int j = 0; j < 2; ++j) {
        int row = (w * 2 + j) * 8 + (l >> 3);
        int swz = ((l & 7) * 16) ^ (((l >> 3) & 7) << 4);
        aGlb[j] = (const char*)imgBase + (size_t)row * 4096 + swz;
    }

    float invT = 0.f;
    if (!WS) invT = inv_norm[b * NT + tid];

    f32x4 acc[4][8];
#pragma unroll
    for (int mi = 0; mi < 4; ++mi)
#pragma unroll
        for (int nj = 0; nj < 8; ++nj) acc[mi][nj] = (f32x4)0.f;

#define ISSUE(KT, BUF)                                                        \
    {                                                                         \
        const char* bs = bSrc + (size_t)(KT) * 32768;                         \
        char* bd = (char*)&sm.m.sB[BUF][0];                                   \
        _Pragma("unroll")                                                     \
        for (int i = 0; i < 4; ++i)                                           \
            gl_lds16(bs + (w * 4 + i) * 1024 + l * 16, bd + (w * 4 + i) * 1024); \
        char* ad = (char*)&sm.m.sA[BUF][0];                                   \
        _Pragma("unroll")                                                     \
        for (int j = 0; j < 2; ++j)                                           \
            gl_lds16(aGlb[j] + (size_t)(KT) * 128, ad + (w * 2 + j) * 1024);  \
    }
#define COMPUTE(BUF)                                                          \
    {                                                                         \
        const char* aB = (const char*)&sm.m.sA[BUF][0];                       \
        const char* bB = (const char*)&sm.m.sB[BUF][0];                       \
        f16x8 af[4];                                                          \
        _Pragma("unroll")                                                     \
        for (int mi = 0; mi < 4; ++mi) {                                      \
            int row = wm * 64 + mi * 16 + ln;                                 \
            int sw  = (row & 7) << 4;                                         \
            float4 a0 = *reinterpret_cast<const float4*>(                     \
                aB + row * 128 + ((q * 32) ^ sw));                            \
            float4 a1 = *reinterpret_cast<const float4*>(                     \
                aB + row * 128 + ((q * 32 + 16) ^ sw));                       \
            af[mi] = packA(a0, a1);                                           \
        }                                                                     \
        _Pragma("unroll")                                                     \
        for (int nj = 0; nj < 8; ++nj) {                                      \
            f16x8 bf = *reinterpret_cast<const f16x8*>(                       \
                bB + q * 8192 + (wn * 128 + nj * 16 + ln) * 16);              \
            _Pragma("unroll")                                                 \
            for (int mi = 0; mi < 4; ++mi)                                    \
                acc[mi][nj] = __builtin_amdgcn_mfma_f32_16x16x32_f16(         \
                    af[mi], bf, acc[mi][nj], 0, 0, 0);                        \
        }                                                                     \
    }
#define SYNCN(N)                                                              \
    asm volatile("s_waitcnt vmcnt(" #N ")" ::: "memory");                     \
    __builtin_amdgcn_sched_barrier(0);                                        \
    __builtin_amdgcn_s_barrier();                                             \
    asm volatile("" ::: "memory");
// one pipeline tile: issue KT+2 into BUF2, compute BUF, counted wait, barrier
#define TILE(KT, BUF, BUF2)                                                   \
    {                                                                         \
        const bool mI = ((KT) + 2 < NKT);                                     \
        if (mI) ISSUE((KT) + 2, BUF2)                                         \
        COMPUTE(BUF)                                                          \
        if (mI) { SYNCN(6) } else { SYNCN(0) }                                \
    }

    if (WS) {
        // prologue: tiles 0 and 1 in flight; wait tile 0 (6 of tile 1 remain)
        ISSUE(0, 0)
        ISSUE(1, 1)
        SYNCN(6)
        // main loop: ring of 3, 11 iterations cover kt = 0..31
#pragma unroll 1
        for (int it = 0; it < 11; ++it) {
            const int kt0 = it * 3;
            TILE(kt0, 0, 2)
            if (kt0 + 1 < NKT) TILE(kt0 + 1, 1, 0)
            if (kt0 + 2 < NKT) TILE(kt0 + 2, 2, 1)
        }
    } else {
        // fallback: single-buffer full-drain (correctness path)
#pragma unroll 1
        for (int kt = 0; kt < NKT; ++kt) {
            __syncthreads();
            // B: thread stages text row tid (32 k) into [q][t][8] image
            const float* bp = textBase + (size_t)tid * CD + kt * BK;
#pragma unroll
            for (int j = 0; j < 4; ++j) {
                float4 v0 = *reinterpret_cast<const float4*>(bp + j * 8);
                float4 v1 = *reinterpret_cast<const float4*>(bp + j * 8 + 4);
                f16x8 h;
                h[0] = (_Float16)(v0.x * invT); h[1] = (_Float16)(v0.y * invT);
                h[2] = (_Float16)(v0.z * invT); h[3] = (_Float16)(v0.w * invT);
                h[4] = (_Float16)(v1.x * invT); h[5] = (_Float16)(v1.y * invT);
                h[6] = (_Float16)(v1.z * invT); h[7] = (_Float16)(v1.w * invT);
                *reinterpret_cast<f16x8*>(
                    (char*)&sm.m.sB[0][0] + j * 8192 + tid * 16) = h;
            }
            // A: thread stages row tid>>2, 8 floats at seg, swizzled write
            {
                int row = tid >> 2, kseg = tid & 3;
                int sw  = (row & 7) << 4;
                const float* ap = imgBase + (size_t)row * CD + kt * BK + kseg * 8;
                float4 a0 = *reinterpret_cast<const float4*>(ap);
                float4 a1 = *reinterpret_cast<const float4*>(ap + 4);
                char* aB = (char*)&sm.m.sA[0][0];
                *reinterpret_cast<float4*>(aB + row * 128 + ((kseg * 32) ^ sw)) = a0;
                *reinterpret_cast<float4*>(aB + row * 128 + ((kseg * 32 + 16) ^ sw)) = a1;
            }
            __syncthreads();
            COMPUTE(0)
        }
    }
#undef ISSUE
#undef COMPUTE
#undef SYNCN
#undef TILE

    __syncthreads();   // safe transition to epilogue union

    // --- approx argmax per row WITH index (first-occurrence tie rule) ---
    // C/D layout: col = ln (text), row = q*4 + r  [m89]
#pragma unroll
    for (int mi = 0; mi < 4; ++mi) {
#pragma unroll
        for (int r = 0; r < 4; ++r) {
            float m  = acc[mi][0][r];
            int   bi = wn * 128 + ln;
#pragma unroll
            for (int nj = 1; nj < 8; ++nj) {
                float v = acc[mi][nj][r];
                int  ci = wn * 128 + nj * 16 + ln;
                if (v > m) { m = v; bi = ci; }
            }
#pragma unroll
            for (int off = 1; off < 16; off <<= 1) {
                float om = __shfl_xor(m, off);
                int   oi = __shfl_xor(bi, off);
                if (om > m || (om == m && oi < bi)) { m = om; bi = oi; }
            }
            if (ln == 0) {
                int rl = wm * 64 + mi * 16 + q * 4 + r;
                sm.e.pval[wn * BM + rl] = m;
                sm.e.pidx[wn * BM + rl] = bi;
            }
        }
    }
    __syncthreads();

    // merge 4 wn slices (ascending wn = ascending text -> first-occurrence)
    if (tid < BM) {
        float bv = sm.e.pval[tid];
        int   bi = sm.e.pidx[tid];
#pragma unroll
        for (int ww = 1; ww < 4; ++ww) {
            float v  = sm.e.pval[ww * BM + tid];
            int   i2 = sm.e.pidx[ww * BM + tid];
            if (v > bv || (v == bv && i2 < bi)) { bv = v; bi = i2; }
        }
        sm.e.sval[tid]   = bv;
        sm.e.sidx[tid]   = bi;    // exact answer if rowcnt==1
        sm.e.rowcnt[tid] = 0;
        sm.e.keys[tid]   = 0ull;
    }
    if (tid == 0) sm.e.cnt = 0;
    __syncthreads();

    // candidate collection: all (row,t) with approx >= rowmax - DELTA
    {
        float thr[4][4];
#pragma unroll
        for (int mi = 0; mi < 4; ++mi)
#pragma unroll
            for (int r = 0; r < 4; ++r)
                thr[mi][r] = sm.e.sval[wm * 64 + mi * 16 + q * 4 + r] - DELTA;
#pragma unroll
        for (int mi = 0; mi < 4; ++mi)
#pragma unroll
            for (int nj = 0; nj < 8; ++nj)
#pragma unroll
                for (int r = 0; r < 4; ++r) {
                    if (acc[mi][nj][r] >= thr[mi][r]) {
                        int rl = wm * 64 + mi * 16 + q * 4 + r;
                        int t  = wn * 128 + nj * 16 + ln;
                        atomicAdd(&sm.e.rowcnt[rl], 1);
                        int slot = atomicAdd(&sm.e.cnt, 1);
                        if (slot < MAXC) sm.e.cand[slot] = (rl << 16) | t;
                    }
                }
    }
    __syncthreads();

    // exact fp32 refine, only rows with >=2 candidates (replicates R1
    // arithmetic exactly -> matches np argmax; proven R3-R14)
    {
        int n = sm.e.cnt < MAXC ? sm.e.cnt : MAXC;
        for (int c = tid; c < n; c += 512) {
            int rt = sm.e.cand[c];
            int rl = rt >> 16;
            int t  = rt & 0xFFFF;
            if (sm.e.rowcnt[rl] < 2) continue;
            const float* ap = imgBase  + (size_t)rl * CD;
            const float* bp = textBase + (size_t)t  * CD;
            float s = inv_norm[b * NT + t];
            float accv = 0.f;
#pragma unroll 2
            for (int k = 0; k < CD; k += 4) {
                float4 av = *reinterpret_cast<const float4*>(ap + k);
                float4 bv = *reinterpret_cast<const float4*>(bp + k);
                accv = fmaf(av.x, bv.x * s, accv);
                accv = fmaf(av.y, bv.y * s, accv);
                accv = fmaf(av.z, bv.z * s, accv);
                accv = fmaf(av.w, bv.w * s, accv);
            }
            unsigned ub = __float_as_uint(accv);
            unsigned su = ub ^ ((unsigned)((int)ub >> 31) | 0x80000000u);
            unsigned long long key =
                ((unsigned long long)su << 32) | (unsigned)(NT - 1 - t);
            atomicMax(&sm.e.keys[rl], key);
        }
    }
    __syncthreads();

    // write per-row winning index to global (128 ints/block)
    if (tid < BM) {
        int v = sm.e.sidx[tid];
        if (sm.e.rowcnt[tid] > 1)
            v = NT - 1 - (int)(sm.e.keys[tid] & 0xFFFFFFFFull);
        gsidx[(size_t)b * NI + row0 + tid] = v;
    }
}

// Kernel 3: pure streaming gather. Block = 16 rows; text rows L2/L3-hot,
// 64-KB coalesced float4 writes per block. 2048 blocks.
__global__ __launch_bounds__(256) void gather_kernel(const float* __restrict__ text,
                                                     const int* __restrict__ gsidx,
                                                     float* __restrict__ out) {
    __shared__ int idx[16];
    const int tid  = threadIdx.x;
    const int b    = blockIdx.x & 7;
    const int row0 = (blockIdx.x >> 3) * 16;

    if (tid < 16) idx[tid] = gsidx[(size_t)b * NI + row0 + tid];
    __syncthreads();

    const float* textBase = text + (size_t)b * NT * CD;
    float* outBase = out + ((size_t)b * NI + row0) * CD;
#pragma unroll 1
    for (int rr = 0; rr < 16; rr += 2) {
        const float4* s0 = reinterpret_cast<const float4*>(textBase + (size_t)idx[rr]     * CD);
        const float4* s1 = reinterpret_cast<const float4*>(textBase + (size_t)idx[rr + 1] * CD);
        float4 v0 = s0[tid];
        float4 v1 = s1[tid];
        reinterpret_cast<float4*>(outBase + (size_t)(rr    ) * CD)[tid] = v0;
        reinterpret_cast<float4*>(outBase + (size_t)(rr + 1) * CD)[tid] = v1;
    }
}

extern "C" void kernel_launch(void* const* d_in, const int* in_sizes, int n_in,
                              void* d_out, int out_size, void* d_ws, size_t ws_size,
                              hipStream_t stream) {
    const float* img  = (const float*)d_in[0];   // [8,4096,1024] fp32
    const float* text = (const float*)d_in[1];   // [8,512,1024] fp32
    float* out      = (float*)d_out;             // [8,4096,1024] fp32
    float* inv_norm = (float*)d_ws;
    int*   gsidx    = (int*)((char*)d_ws + WS_NORM_B);
    _Float16* wsB   = (_Float16*)((char*)d_ws + WSB_OFF);

    const int gridGemm = NI / BM * B_;   // 256 = 1 block/CU
    if (ws_size >= NEED_FULL) {
        prep_text_kernel<true><<<dim3(B_ * NT / 4), 256, 0, stream>>>(text, inv_norm, wsB);
        gemm_kernel<1><<<dim3(gridGemm), 512, 0, stream>>>(img, text, inv_norm, wsB, gsidx);
    } else {
        prep_text_kernel<false><<<dim3(B_ * NT / 4), 256, 0, stream>>>(text, inv_norm, wsB);
        gemm_kernel<0><<<dim3(gridGemm), 512, 0, stream>>>(img, text, inv_norm, wsB, gsidx);
    }
    gather_kernel<<<dim3(B_ * NI / 16), 256, 0, stream>>>(text, gsidx, out);
}